// Round 4
// baseline (169.636 us; speedup 1.0000x reference)
//
#include <hip/hip_runtime.h>
#include <math.h>

#define BB   4
#define MM   1024
#define NN   1024
#define DD   9
#define KSEL 16
#define NROW (BB * MM)        // 4096 row-slots per phase
#define NBLK (2 * NROW / 4)   // 2048 blocks, 4 waves (row-slots) each

// Workspace. acc_i/acc_o/ticket are zeroed by prep_kernel (runs first in the
// graph) before dist_kernel touches them. yT at offset 32 => 16B-aligned for
// float4 loads (planes are 4 KB apart).
struct Ws {
  double acc_i;               // sum of intra row top-16 sums
  double acc_o;               // sum of outer row top-16 sums
  unsigned ticket;            // last-block-done counter
  unsigned pad[3];
  float yT[BB * DD * NN];     // transposed y_pred: [b][p][j]
  float qy[BB * NN];          // y_j^T Cinv y_j
  float cnt;
  float mean[DD];
  float cinv[DD * DD];
};

// ---------------------------------------------------------------------------
// Kernel 1 (1 block x 256): (A) masked moment stats over all 4096 target
// rows; (B) 9x9 fp64 Gauss-Jordan inverse on wave 0, lane p owns augmented
// row p, fully unrolled => register-resident (cov of ~2048 N(0,1) samples is
// SPD, diag~1 => no pivoting needed, pinv == inverse); (C) qy[j] and the
// SoA transpose yT; zero the dist-kernel accumulators.
// ---------------------------------------------------------------------------
__global__ __launch_bounds__(256) void prep_kernel(
    const float* __restrict__ outputs, const float* __restrict__ targets,
    const int* __restrict__ mask, Ws* __restrict__ ws) {
  const int tid = threadIdx.x;
  __shared__ float lds[4][55];
  __shared__ double Sd[55];
  __shared__ float Cs[DD * DD];
  __shared__ float Ms[DD];

  // --- A: moments ---------------------------------------------------------
  float acc[55];
#pragma unroll
  for (int k = 0; k < 55; ++k) acc[k] = 0.f;
#pragma unroll
  for (int it = 0; it < NROW / 256; ++it) {
    const int r = it * 256 + tid;
    if (mask[r] != 0) {
      float t[DD];
#pragma unroll
      for (int k = 0; k < DD; ++k) t[k] = targets[r * DD + k];
      acc[0] += 1.f;
#pragma unroll
      for (int k = 0; k < DD; ++k) acc[1 + k] += t[k];
      int u = 10;
#pragma unroll
      for (int p = 0; p < DD; ++p)
#pragma unroll
        for (int q = p; q < DD; ++q) acc[u++] += t[p] * t[q];
    }
  }
#pragma unroll
  for (int k = 0; k < 55; ++k) {
    float v = acc[k];
#pragma unroll
    for (int off = 32; off > 0; off >>= 1) v += __shfl_down(v, off, 64);
    if ((tid & 63) == 0) lds[tid >> 6][k] = v;
  }
  __syncthreads();
  if (tid < 55)
    Sd[tid] = (double)lds[0][tid] + (double)lds[1][tid] + (double)lds[2][tid] +
              (double)lds[3][tid];
  __syncthreads();

  // --- B: inverse (wave 0) ------------------------------------------------
  if (tid < 64) {
    const int lane = tid;
    const double cnt = Sd[0];
    const int p = (lane < DD) ? lane : 0;  // junk lanes mirror row 0
    double row[2 * DD];
    {
      const double mu_p = Sd[1 + p] / cnt;
#pragma unroll
      for (int q = 0; q < DD; ++q) {
        const int pp = (p < q) ? p : q;
        const int qq = (p < q) ? q : p;
        const int idx = 10 + 9 * pp - (pp * (pp - 1)) / 2 + (qq - pp);
        const double mu_q = Sd[1 + q] / cnt;
        row[q] = (Sd[idx] - cnt * mu_p * mu_q) / (cnt - 1.0);
        row[DD + q] = (p == q) ? 1.0 : 0.0;
      }
    }
#pragma unroll
    for (int c = 0; c < DD; ++c) {
      const double diag = __shfl(row[c], c, 64);
      const double dinv = 1.0 / diag;
      if (lane == c) {
#pragma unroll
        for (int q = 0; q < 2 * DD; ++q) row[q] *= dinv;
      }
      const double f = (lane == c) ? 0.0 : row[c];
#pragma unroll
      for (int q = 0; q < 2 * DD; ++q) {
        const double pv = __shfl(row[q], c, 64);
        row[q] -= f * pv;
      }
    }
    if (lane < DD) {
#pragma unroll
      for (int q = 0; q < DD; ++q) {
        const float cf = (float)row[DD + q];
        Cs[lane * DD + q] = cf;
        ws->cinv[lane * DD + q] = cf;
      }
    }
    if (lane == 0) {
      ws->cnt = (float)cnt;
#pragma unroll
      for (int q = 0; q < DD; ++q) {
        const float m = (float)(Sd[1 + q] / cnt);
        Ms[q] = m;
        ws->mean[q] = m;
      }
      ws->acc_i = 0.0;
      ws->acc_o = 0.0;
      ws->ticket = 0u;
    }
  }
  __syncthreads();

  // --- C: qy + transpose --------------------------------------------------
  float C[DD * DD];
#pragma unroll
  for (int k = 0; k < DD * DD; ++k) C[k] = Cs[k];
  for (int j = tid; j < BB * NN; j += 256) {
    const int b = j >> 10;
    const int jj = j & (NN - 1);
    float y[DD];
#pragma unroll
    for (int k = 0; k < DD; ++k) y[k] = outputs[j * DD + k];
    float q = 0.f;
#pragma unroll
    for (int p = 0; p < DD; ++p) {
      float s = 0.f;
#pragma unroll
      for (int t = 0; t < DD; ++t) s += C[p * DD + t] * y[t];
      q += y[p] * s;
      ws->yT[(b * DD + p) * NN + jj] = y[p];  // coalesced per p across threads
    }
    ws->qy[j] = q;
  }
}

// ---------------------------------------------------------------------------
// Kernel 2: one wave per row-slot, 4 waves/block. Distances via coalesced
// float4 loads from the SoA planes (lane owns j = lane*16..lane*16+15 -- the
// j->lane mapping is free since only values are summed). Top-16 = per-lane
// bitonic sort + 6 shfl_xor half-cleaner merge rounds (branch-free, high
// ILP). Block reduce -> one fp64 atomicAdd; last block (ticket) finalizes.
// ---------------------------------------------------------------------------
__global__ __launch_bounds__(256) void dist_kernel(
    const float* __restrict__ outputs, const float* __restrict__ targets,
    const int* __restrict__ mask, Ws* __restrict__ ws,
    float* __restrict__ out) {
  const int wv = threadIdx.x >> 6;
  const int lane = threadIdx.x & 63;
  const int s = blockIdx.x * 4 + wv;
  const bool is_intra = (s < NROW);  // uniform per block (4 | 4096)
  const int r = s & (NROW - 1);
  const int b = r >> 10;

  float total = 0.f;
  const bool active = !(is_intra && mask[r] == 0);
  if (active) {
    float a[DD];
    if (is_intra) {
#pragma unroll
      for (int k = 0; k < DD; ++k) a[k] = targets[r * DD + k] - ws->mean[k];
    } else {
#pragma unroll
      for (int k = 0; k < DD; ++k) a[k] = outputs[r * DD + k] + ws->mean[k];
    }
    float w[DD];
    float qa = 0.f;
#pragma unroll
    for (int p = 0; p < DD; ++p) {
      float acc = 0.f;
#pragma unroll
      for (int t = 0; t < DD; ++t) acc += ws->cinv[p * DD + t] * a[t];
      w[p] = acc;
      qa += a[p] * acc;
    }

    // distances: v[c*4+e] for j = lane*16 + c*4 + e
    float v[16];
#pragma unroll
    for (int k = 0; k < 16; ++k) v[k] = 0.f;
    const float* __restrict__ yTb = ws->yT + (size_t)b * DD * NN;
#pragma unroll
    for (int p = 0; p < DD; ++p) {
      const float4* __restrict__ pl =
          (const float4*)(yTb + (size_t)p * NN) + lane * 4;
#pragma unroll
      for (int c = 0; c < 4; ++c) {
        const float4 y4 = pl[c];
        v[c * 4 + 0] += w[p] * y4.x;
        v[c * 4 + 1] += w[p] * y4.y;
        v[c * 4 + 2] += w[p] * y4.z;
        v[c * 4 + 3] += w[p] * y4.w;
      }
    }
    const float4* __restrict__ q4 =
        (const float4*)(ws->qy + (size_t)b * NN) + lane * 4;
#pragma unroll
    for (int c = 0; c < 4; ++c) {
      const float4 qv = q4[c];
      v[c * 4 + 0] = qa + qv.x - 2.f * v[c * 4 + 0];
      v[c * 4 + 1] = qa + qv.y - 2.f * v[c * 4 + 1];
      v[c * 4 + 2] = qa + qv.z - 2.f * v[c * 4 + 2];
      v[c * 4 + 3] = qa + qv.w - 2.f * v[c * 4 + 3];
    }

    // per-lane bitonic sort ascending (all indices static after unroll)
#pragma unroll
    for (int k = 2; k <= 16; k <<= 1) {
#pragma unroll
      for (int j = k >> 1; j > 0; j >>= 1) {
#pragma unroll
        for (int i = 0; i < 16; ++i) {
          const int l = i ^ j;
          if (l > i) {
            const bool up = ((i & k) == 0);
            const float lo = fminf(v[i], v[l]);
            const float hi = fmaxf(v[i], v[l]);
            v[i] = up ? lo : hi;
            v[l] = up ? hi : lo;
          }
        }
      }
    }

    // 6 cross-lane merge rounds: keep 16 smallest of self+partner.
    // Half-cleaner: min(A[i], B[15-i]) is bitonic and contains the 16
    // smallest of A (asc) union B (asc); re-sort with a 4-stage bitonic merge.
#pragma unroll
    for (int off = 1; off < 64; off <<= 1) {
      float pr[16];
#pragma unroll
      for (int i = 0; i < 16; ++i) pr[i] = __shfl_xor(v[i], off, 64);
#pragma unroll
      for (int i = 0; i < 16; ++i) v[i] = fminf(v[i], pr[15 - i]);
#pragma unroll
      for (int j = 8; j > 0; j >>= 1) {
#pragma unroll
        for (int i = 0; i < 16; ++i) {
          const int l = i ^ j;
          if (l > i) {
            const float lo = fminf(v[i], v[l]);
            const float hi = fmaxf(v[i], v[l]);
            v[i] = lo;
            v[l] = hi;
          }
        }
      }
    }
#pragma unroll
    for (int k = 0; k < 16; ++k) total += v[k];
  }

  __shared__ float bsum[4];
  if (lane == 0) bsum[wv] = total;
  __syncthreads();
  if (threadIdx.x == 0) {
    const double sblk = (double)bsum[0] + (double)bsum[1] + (double)bsum[2] +
                        (double)bsum[3];
    atomicAdd(is_intra ? &ws->acc_i : &ws->acc_o, sblk);
    __threadfence();
    const unsigned t = atomicAdd(&ws->ticket, 1u);
    if (t == NBLK - 1) {  // last block: read back via atomic RMW (coherent)
      __threadfence();
      const double si = atomicAdd(&ws->acc_i, 0.0);
      const double so = atomicAdd(&ws->acc_o, 0.0);
      const float intra = (float)(si / (double)ws->cnt);
      const float outer = (float)(so / (double)(NROW * KSEL));
      out[0] = intra;
      out[1] = intra;
      out[2] = outer;
    }
  }
}

extern "C" void kernel_launch(void* const* d_in, const int* in_sizes, int n_in,
                              void* d_out, int out_size, void* d_ws,
                              size_t ws_size, hipStream_t stream) {
  const float* outputs = (const float*)d_in[0];  // (4,1024,9) f32
  const float* targets = (const float*)d_in[1];  // (4,1024,9) f32
  const int* mask = (const int*)d_in[2];         // (4,1024)
  Ws* ws = (Ws*)d_ws;
  float* out = (float*)d_out;

  prep_kernel<<<1, 256, 0, stream>>>(outputs, targets, mask, ws);
  dist_kernel<<<NBLK, 256, 0, stream>>>(outputs, targets, mask, ws, out);
}

// Round 5
// 100.781 us; speedup vs baseline: 1.6832x; 1.6832x over previous
//
#include <hip/hip_runtime.h>
#include <math.h>

#define BB   4
#define MM   1024
#define NN   1024
#define DD   9
#define KSEL 16
#define NROW (BB * MM)        // 4096 row-slots per phase
#define NSLOT (2 * NROW)
#define NBLK (NSLOT / 4)      // 2048 blocks, 4 waves (row-slots) each

// Workspace. yT first => 16B-aligned float4 planes. Every field written
// before read (masked rows write rowsum=0) => no memset, no atomics.
struct Ws {
  float yT[BB * DD * NN];     // [b][p][j] SoA planes (4 KB each)
  float qy[BB * NN];          // y_j^T Cinv y_j
  float rowsum[NSLOT];        // per-row top-16 sum
  float part[16][55];         // per-block moment partials
  float cnt;
  float mean[DD];
  float cinv[DD * DD];
};

// ---------------------------------------------------------------------------
// Kernel 1: 16 blocks x 256, one target row/thread. 55 masked moment partials
// -> wave shuffle reduce -> LDS across waves -> part[block][k].
// ---------------------------------------------------------------------------
__global__ __launch_bounds__(256) void stats_kernel(
    const float* __restrict__ targets, const int* __restrict__ mask,
    Ws* __restrict__ ws) {
  const int tid = threadIdx.x;
  const int r = blockIdx.x * 256 + tid;

  float acc[55];
#pragma unroll
  for (int k = 0; k < 55; ++k) acc[k] = 0.f;
  if (mask[r] != 0) {
    float t[DD];
#pragma unroll
    for (int k = 0; k < DD; ++k) t[k] = targets[r * DD + k];
    acc[0] = 1.f;
#pragma unroll
    for (int k = 0; k < DD; ++k) acc[1 + k] = t[k];
    int u = 10;
#pragma unroll
    for (int p = 0; p < DD; ++p)
#pragma unroll
      for (int q = p; q < DD; ++q) acc[u++] = t[p] * t[q];
  }

  __shared__ float lds[4][55];
#pragma unroll
  for (int k = 0; k < 55; ++k) {
    float v = acc[k];
#pragma unroll
    for (int off = 32; off > 0; off >>= 1) v += __shfl_down(v, off, 64);
    if ((tid & 63) == 0) lds[tid >> 6][k] = v;
  }
  __syncthreads();
  if (tid < 55)
    ws->part[blockIdx.x][tid] =
        lds[0][tid] + lds[1][tid] + lds[2][tid] + lds[3][tid];
}

// ---------------------------------------------------------------------------
// Kernel 2: one wave. Sum partials (fp64); lane p owns augmented row p of
// [cov | I]; fully-unrolled fp64 Gauss-Jordan (register-resident; cov of
// ~2048 N(0,1) samples is SPD, diag~1 => no pivoting, pinv == inverse).
// ---------------------------------------------------------------------------
__global__ __launch_bounds__(64) void invert_kernel(Ws* __restrict__ ws) {
  const int lane = threadIdx.x;
  __shared__ double Sd[55];
  if (lane < 55) {
    double s = 0.0;
#pragma unroll
    for (int b = 0; b < 16; ++b) s += (double)ws->part[b][lane];
    Sd[lane] = s;
  }
  __syncthreads();

  const double cnt = Sd[0];
  const int p = (lane < DD) ? lane : 0;  // junk lanes mirror row 0
  double row[2 * DD];
  {
    const double mu_p = Sd[1 + p] / cnt;
#pragma unroll
    for (int q = 0; q < DD; ++q) {
      const int pp = (p < q) ? p : q;
      const int qq = (p < q) ? q : p;
      const int idx = 10 + 9 * pp - (pp * (pp - 1)) / 2 + (qq - pp);
      row[q] = (Sd[idx] - cnt * mu_p * (Sd[1 + q] / cnt)) / (cnt - 1.0);
      row[DD + q] = (p == q) ? 1.0 : 0.0;
    }
  }
#pragma unroll
  for (int c = 0; c < DD; ++c) {
    const double diag = __shfl(row[c], c, 64);
    const double dinv = 1.0 / diag;
    if (lane == c) {
#pragma unroll
      for (int q = 0; q < 2 * DD; ++q) row[q] *= dinv;
    }
    const double f = (lane == c) ? 0.0 : row[c];
#pragma unroll
    for (int q = 0; q < 2 * DD; ++q) {
      const double pv = __shfl(row[q], c, 64);
      row[q] -= f * pv;
    }
  }
  if (lane < DD) {
#pragma unroll
    for (int q = 0; q < DD; ++q)
      ws->cinv[lane * DD + q] = (float)row[DD + q];
  }
  if (lane == 0) {
    ws->cnt = (float)cnt;
#pragma unroll
    for (int q = 0; q < DD; ++q) ws->mean[q] = (float)(Sd[1 + q] / cnt);
  }
}

// ---------------------------------------------------------------------------
// Kernel 3: 16 blocks x 256, one y_pred row/thread: qy[j] = y^T Cinv y and
// the SoA transpose yT[b][p][j] (stores coalesced per p).
// ---------------------------------------------------------------------------
__global__ __launch_bounds__(256) void qyt_kernel(
    const float* __restrict__ outputs, Ws* __restrict__ ws) {
  const int j = blockIdx.x * 256 + threadIdx.x;
  const int b = j >> 10;
  const int jj = j & (NN - 1);
  float C[DD * DD];
#pragma unroll
  for (int k = 0; k < DD * DD; ++k) C[k] = ws->cinv[k];
  float y[DD];
#pragma unroll
  for (int k = 0; k < DD; ++k) y[k] = outputs[j * DD + k];
  float q = 0.f;
#pragma unroll
  for (int p = 0; p < DD; ++p) {
    float s = 0.f;
#pragma unroll
    for (int t = 0; t < DD; ++t) s += C[p * DD + t] * y[t];
    q += y[p] * s;
    ws->yT[(b * DD + p) * NN + jj] = y[p];
  }
  ws->qy[j] = q;
}

// ---------------------------------------------------------------------------
// Kernel 4: one wave per row-slot, 4 waves/block; no LDS, no __syncthreads,
// no atomics. Lane owns j = c*256 + lane*4 + e => float4 index c*64+lane =>
// 16 B lane stride, fully coalesced (j->lane mapping free: values only).
// Top-16 = per-lane bitonic sort + 6 shfl_xor half-cleaner merge rounds
// (validated R4). Lane 0 stores rowsum[s].
// ---------------------------------------------------------------------------
__global__ __launch_bounds__(256) void dist_kernel(
    const float* __restrict__ outputs, const float* __restrict__ targets,
    const int* __restrict__ mask, Ws* __restrict__ ws) {
  const int wv = threadIdx.x >> 6;
  const int lane = threadIdx.x & 63;
  const int s = blockIdx.x * 4 + wv;
  const bool is_intra = (s < NROW);  // wave-uniform
  const int r = s & (NROW - 1);
  const int b = r >> 10;

  if (is_intra && mask[r] == 0) {
    if (lane == 0) ws->rowsum[s] = 0.f;
    return;
  }

  float a[DD];
  if (is_intra) {
#pragma unroll
    for (int k = 0; k < DD; ++k) a[k] = targets[r * DD + k] - ws->mean[k];
  } else {
#pragma unroll
    for (int k = 0; k < DD; ++k) a[k] = outputs[r * DD + k] + ws->mean[k];
  }
  float w[DD];
  float qa = 0.f;
#pragma unroll
  for (int p = 0; p < DD; ++p) {
    float acc = 0.f;
#pragma unroll
    for (int t = 0; t < DD; ++t) acc += ws->cinv[p * DD + t] * a[t];
    w[p] = acc;
    qa += a[p] * acc;
  }

  float v[16];
#pragma unroll
  for (int k = 0; k < 16; ++k) v[k] = 0.f;
  const float* __restrict__ yTb = ws->yT + (size_t)b * DD * NN;
#pragma unroll
  for (int p = 0; p < DD; ++p) {
    const float4* __restrict__ pl = (const float4*)(yTb + (size_t)p * NN);
#pragma unroll
    for (int c = 0; c < 4; ++c) {
      const float4 y4 = pl[c * 64 + lane];
      v[c * 4 + 0] += w[p] * y4.x;
      v[c * 4 + 1] += w[p] * y4.y;
      v[c * 4 + 2] += w[p] * y4.z;
      v[c * 4 + 3] += w[p] * y4.w;
    }
  }
  {
    const float4* __restrict__ q4 = (const float4*)(ws->qy + (size_t)b * NN);
#pragma unroll
    for (int c = 0; c < 4; ++c) {
      const float4 qv = q4[c * 64 + lane];
      v[c * 4 + 0] = qa + qv.x - 2.f * v[c * 4 + 0];
      v[c * 4 + 1] = qa + qv.y - 2.f * v[c * 4 + 1];
      v[c * 4 + 2] = qa + qv.z - 2.f * v[c * 4 + 2];
      v[c * 4 + 3] = qa + qv.w - 2.f * v[c * 4 + 3];
    }
  }

  // per-lane bitonic sort ascending (static indices after unroll)
#pragma unroll
  for (int k = 2; k <= 16; k <<= 1) {
#pragma unroll
    for (int j = k >> 1; j > 0; j >>= 1) {
#pragma unroll
      for (int i = 0; i < 16; ++i) {
        const int l = i ^ j;
        if (l > i) {
          const bool up = ((i & k) == 0);
          const float lo = fminf(v[i], v[l]);
          const float hi = fmaxf(v[i], v[l]);
          v[i] = up ? lo : hi;
          v[l] = up ? hi : lo;
        }
      }
    }
  }

  // 6 cross-lane rounds: half-cleaner min(A[i],B[15-i]) keeps the 16
  // smallest of two ascending 16-lists as a bitonic seq; 4-stage re-merge.
#pragma unroll
  for (int off = 1; off < 64; off <<= 1) {
    float pr[16];
#pragma unroll
    for (int i = 0; i < 16; ++i) pr[i] = __shfl_xor(v[i], off, 64);
#pragma unroll
    for (int i = 0; i < 16; ++i) v[i] = fminf(v[i], pr[15 - i]);
#pragma unroll
    for (int j = 8; j > 0; j >>= 1) {
#pragma unroll
      for (int i = 0; i < 16; ++i) {
        const int l = i ^ j;
        if (l > i) {
          const float lo = fminf(v[i], v[l]);
          const float hi = fmaxf(v[i], v[l]);
          v[i] = lo;
          v[l] = hi;
        }
      }
    }
  }

  float total = v[0];
#pragma unroll
  for (int k = 1; k < 16; ++k) total += v[k];
  if (lane == 0) ws->rowsum[s] = total;
}

// ---------------------------------------------------------------------------
// Kernel 5: one block; reduce 8192 row sums -> three scalars.
// ---------------------------------------------------------------------------
__global__ __launch_bounds__(256) void finalize_kernel(
    const Ws* __restrict__ ws, float* __restrict__ out) {
  const int tid = threadIdx.x;
  double li = 0.0, lo = 0.0;
  for (int k = tid; k < NROW; k += 256) {
    li += (double)ws->rowsum[k];
    lo += (double)ws->rowsum[NROW + k];
  }
#pragma unroll
  for (int off = 32; off > 0; off >>= 1) {
    li += __shfl_down(li, off, 64);
    lo += __shfl_down(lo, off, 64);
  }
  __shared__ double lds_i[4], lds_o[4];
  if ((tid & 63) == 0) {
    lds_i[tid >> 6] = li;
    lds_o[tid >> 6] = lo;
  }
  __syncthreads();
  if (tid == 0) {
    const double si = lds_i[0] + lds_i[1] + lds_i[2] + lds_i[3];
    const double so = lds_o[0] + lds_o[1] + lds_o[2] + lds_o[3];
    const float intra = (float)(si / (double)ws->cnt);
    const float outer = (float)(so / (double)(NROW * KSEL));
    out[0] = intra;
    out[1] = intra;
    out[2] = outer;
  }
}

extern "C" void kernel_launch(void* const* d_in, const int* in_sizes, int n_in,
                              void* d_out, int out_size, void* d_ws,
                              size_t ws_size, hipStream_t stream) {
  const float* outputs = (const float*)d_in[0];  // (4,1024,9) f32
  const float* targets = (const float*)d_in[1];  // (4,1024,9) f32
  const int* mask = (const int*)d_in[2];         // (4,1024)
  Ws* ws = (Ws*)d_ws;
  float* out = (float*)d_out;

  stats_kernel<<<NROW / 256, 256, 0, stream>>>(targets, mask, ws);
  invert_kernel<<<1, 64, 0, stream>>>(ws);
  qyt_kernel<<<(BB * NN) / 256, 256, 0, stream>>>(outputs, ws);
  dist_kernel<<<NBLK, 256, 0, stream>>>(outputs, targets, mask, ws);
  finalize_kernel<<<1, 256, 0, stream>>>(ws, out);
}

// Round 6
// 97.225 us; speedup vs baseline: 1.7448x; 1.0366x over previous
//
#include <hip/hip_runtime.h>
#include <math.h>

#define BB   4
#define MM   1024
#define NN   1024
#define DD   9
#define KSEL 16
#define NROW (BB * MM)        // 4096 row-slots per phase
#define NSLOT (2 * NROW)
#define NBLK (NSLOT / 4)      // 2048 blocks, 4 waves (row-slots) each

// Workspace. yT first => 16B-aligned float4 planes. Every field written
// before read (masked rows write rowsum=0) => no memset, no atomics.
// NOTE (R5 finding): harness re-poisons the FULL d_ws allocation (268 MB,
// ~40 us at 6.7 TB/s) inside the timed window -> ~45 us session floor.
struct Ws {
  float yT[BB * DD * NN];     // [b][p][j] SoA planes (4 KB each)
  float qy[BB * NN];          // y_j^T Cinv y_j
  float rowsum[NSLOT];        // per-row top-16 sum
  float part[16][55];         // per-block moment partials
  float cnt;
  float mean[DD];
  float cinv[DD * DD];
};

// ---------------------------------------------------------------------------
// Kernel 1: 16 blocks x 256, one target row/thread. 55 masked moment partials
// -> wave shuffle reduce -> LDS across waves -> part[block][k].
// ---------------------------------------------------------------------------
__global__ __launch_bounds__(256) void stats_kernel(
    const float* __restrict__ targets, const int* __restrict__ mask,
    Ws* __restrict__ ws) {
  const int tid = threadIdx.x;
  const int r = blockIdx.x * 256 + tid;

  float acc[55];
#pragma unroll
  for (int k = 0; k < 55; ++k) acc[k] = 0.f;
  if (mask[r] != 0) {
    float t[DD];
#pragma unroll
    for (int k = 0; k < DD; ++k) t[k] = targets[r * DD + k];
    acc[0] = 1.f;
#pragma unroll
    for (int k = 0; k < DD; ++k) acc[1 + k] = t[k];
    int u = 10;
#pragma unroll
    for (int p = 0; p < DD; ++p)
#pragma unroll
      for (int q = p; q < DD; ++q) acc[u++] = t[p] * t[q];
  }

  __shared__ float lds[4][55];
#pragma unroll
  for (int k = 0; k < 55; ++k) {
    float v = acc[k];
#pragma unroll
    for (int off = 32; off > 0; off >>= 1) v += __shfl_down(v, off, 64);
    if ((tid & 63) == 0) lds[tid >> 6][k] = v;
  }
  __syncthreads();
  if (tid < 55)
    ws->part[blockIdx.x][tid] =
        lds[0][tid] + lds[1][tid] + lds[2][tid] + lds[3][tid];
}

// ---------------------------------------------------------------------------
// Kernel 2 (invert fused into qyt): 16 blocks x 256. Wave 0 of EVERY block
// redundantly sums the 16 partials (fp64) and runs the fully-unrolled fp64
// Gauss-Jordan (lane p owns augmented row p; register-resident; cov of ~2048
// N(0,1) samples is SPD, diag~1 => no pivoting, pinv == inverse), broadcasts
// cinv via LDS; then all 256 threads do qy[j] = y^T Cinv y and the SoA
// transpose yT[b][p][j]. Block 0 also publishes cnt/mean/cinv for dist.
// ---------------------------------------------------------------------------
__global__ __launch_bounds__(256) void prep_kernel(
    const float* __restrict__ outputs, Ws* __restrict__ ws) {
  const int tid = threadIdx.x;
  __shared__ double Sd[55];
  __shared__ float Cs[DD * DD];

  if (tid < 55) {
    double s = 0.0;
#pragma unroll
    for (int b = 0; b < 16; ++b) s += (double)ws->part[b][tid];
    Sd[tid] = s;
  }
  __syncthreads();

  if (tid < 64) {
    const int lane = tid;
    const double cnt = Sd[0];
    const int p = (lane < DD) ? lane : 0;  // junk lanes mirror row 0
    double row[2 * DD];
    {
      const double mu_p = Sd[1 + p] / cnt;
#pragma unroll
      for (int q = 0; q < DD; ++q) {
        const int pp = (p < q) ? p : q;
        const int qq = (p < q) ? q : p;
        const int idx = 10 + 9 * pp - (pp * (pp - 1)) / 2 + (qq - pp);
        row[q] = (Sd[idx] - cnt * mu_p * (Sd[1 + q] / cnt)) / (cnt - 1.0);
        row[DD + q] = (p == q) ? 1.0 : 0.0;
      }
    }
#pragma unroll
    for (int c = 0; c < DD; ++c) {
      const double diag = __shfl(row[c], c, 64);
      const double dinv = 1.0 / diag;
      if (lane == c) {
#pragma unroll
        for (int q = 0; q < 2 * DD; ++q) row[q] *= dinv;
      }
      const double f = (lane == c) ? 0.0 : row[c];
#pragma unroll
      for (int q = 0; q < 2 * DD; ++q) {
        const double pv = __shfl(row[q], c, 64);
        row[q] -= f * pv;
      }
    }
    if (lane < DD) {
#pragma unroll
      for (int q = 0; q < DD; ++q) {
        const float cf = (float)row[DD + q];
        Cs[lane * DD + q] = cf;
        if (blockIdx.x == 0) ws->cinv[lane * DD + q] = cf;
      }
    }
    if (lane == 0 && blockIdx.x == 0) {
      ws->cnt = (float)cnt;
#pragma unroll
      for (int q = 0; q < DD; ++q) ws->mean[q] = (float)(Sd[1 + q] / cnt);
    }
  }
  __syncthreads();

  const int j = blockIdx.x * 256 + tid;
  const int b = j >> 10;
  const int jj = j & (NN - 1);
  float C[DD * DD];
#pragma unroll
  for (int k = 0; k < DD * DD; ++k) C[k] = Cs[k];
  float y[DD];
#pragma unroll
  for (int k = 0; k < DD; ++k) y[k] = outputs[j * DD + k];
  float q = 0.f;
#pragma unroll
  for (int p = 0; p < DD; ++p) {
    float s = 0.f;
#pragma unroll
    for (int t = 0; t < DD; ++t) s += C[p * DD + t] * y[t];
    q += y[p] * s;
    ws->yT[(b * DD + p) * NN + jj] = y[p];
  }
  ws->qy[j] = q;
}

// ---------------------------------------------------------------------------
// Kernel 3: one wave per row-slot, 4 waves/block; no LDS, no __syncthreads,
// no atomics. Lane owns j = c*256 + lane*4 + e => float4 index c*64+lane =>
// 16 B lane stride, fully coalesced. Top-16 = per-lane bitonic sort + 6
// shfl_xor half-cleaner rounds; the re-merge after the LAST round is skipped
// (only the sum of the surviving 16 is needed; half-cleaner output already
// holds exactly the top-16 multiset, bitonically ordered).
// ---------------------------------------------------------------------------
__global__ __launch_bounds__(256) void dist_kernel(
    const float* __restrict__ outputs, const float* __restrict__ targets,
    const int* __restrict__ mask, Ws* __restrict__ ws) {
  const int wv = threadIdx.x >> 6;
  const int lane = threadIdx.x & 63;
  const int s = blockIdx.x * 4 + wv;
  const bool is_intra = (s < NROW);  // wave-uniform
  const int r = s & (NROW - 1);
  const int b = r >> 10;

  if (is_intra && mask[r] == 0) {
    if (lane == 0) ws->rowsum[s] = 0.f;
    return;
  }

  float a[DD];
  if (is_intra) {
#pragma unroll
    for (int k = 0; k < DD; ++k) a[k] = targets[r * DD + k] - ws->mean[k];
  } else {
#pragma unroll
    for (int k = 0; k < DD; ++k) a[k] = outputs[r * DD + k] + ws->mean[k];
  }
  float w[DD];
  float qa = 0.f;
#pragma unroll
  for (int p = 0; p < DD; ++p) {
    float acc = 0.f;
#pragma unroll
    for (int t = 0; t < DD; ++t) acc += ws->cinv[p * DD + t] * a[t];
    w[p] = acc;
    qa += a[p] * acc;
  }

  float v[16];
#pragma unroll
  for (int k = 0; k < 16; ++k) v[k] = 0.f;
  const float* __restrict__ yTb = ws->yT + (size_t)b * DD * NN;
#pragma unroll
  for (int p = 0; p < DD; ++p) {
    const float4* __restrict__ pl = (const float4*)(yTb + (size_t)p * NN);
#pragma unroll
    for (int c = 0; c < 4; ++c) {
      const float4 y4 = pl[c * 64 + lane];
      v[c * 4 + 0] += w[p] * y4.x;
      v[c * 4 + 1] += w[p] * y4.y;
      v[c * 4 + 2] += w[p] * y4.z;
      v[c * 4 + 3] += w[p] * y4.w;
    }
  }
  {
    const float4* __restrict__ q4 = (const float4*)(ws->qy + (size_t)b * NN);
#pragma unroll
    for (int c = 0; c < 4; ++c) {
      const float4 qv = q4[c * 64 + lane];
      v[c * 4 + 0] = qa + qv.x - 2.f * v[c * 4 + 0];
      v[c * 4 + 1] = qa + qv.y - 2.f * v[c * 4 + 1];
      v[c * 4 + 2] = qa + qv.z - 2.f * v[c * 4 + 2];
      v[c * 4 + 3] = qa + qv.w - 2.f * v[c * 4 + 3];
    }
  }

  // per-lane bitonic sort ascending (static indices after unroll)
#pragma unroll
  for (int k = 2; k <= 16; k <<= 1) {
#pragma unroll
    for (int j = k >> 1; j > 0; j >>= 1) {
#pragma unroll
      for (int i = 0; i < 16; ++i) {
        const int l = i ^ j;
        if (l > i) {
          const bool up = ((i & k) == 0);
          const float lo = fminf(v[i], v[l]);
          const float hi = fmaxf(v[i], v[l]);
          v[i] = up ? lo : hi;
          v[l] = up ? hi : lo;
        }
      }
    }
  }

  // 6 cross-lane rounds: half-cleaner min(A[i],B[15-i]) keeps the 16
  // smallest of two ascending 16-lists (bitonic order); re-sort with a
  // 4-stage merge only when another round follows.
#pragma unroll
  for (int off = 1; off < 64; off <<= 1) {
    float pr[16];
#pragma unroll
    for (int i = 0; i < 16; ++i) pr[i] = __shfl_xor(v[i], off, 64);
#pragma unroll
    for (int i = 0; i < 16; ++i) v[i] = fminf(v[i], pr[15 - i]);
    if (off < 32) {
#pragma unroll
      for (int j = 8; j > 0; j >>= 1) {
#pragma unroll
        for (int i = 0; i < 16; ++i) {
          const int l = i ^ j;
          if (l > i) {
            const float lo = fminf(v[i], v[l]);
            const float hi = fmaxf(v[i], v[l]);
            v[i] = lo;
            v[l] = hi;
          }
        }
      }
    }
  }

  float total = v[0];
#pragma unroll
  for (int k = 1; k < 16; ++k) total += v[k];
  if (lane == 0) ws->rowsum[s] = total;
}

// ---------------------------------------------------------------------------
// Kernel 4: one block; reduce 8192 row sums -> three scalars.
// ---------------------------------------------------------------------------
__global__ __launch_bounds__(256) void finalize_kernel(
    const Ws* __restrict__ ws, float* __restrict__ out) {
  const int tid = threadIdx.x;
  double li = 0.0, lo = 0.0;
  for (int k = tid; k < NROW; k += 256) {
    li += (double)ws->rowsum[k];
    lo += (double)ws->rowsum[NROW + k];
  }
#pragma unroll
  for (int off = 32; off > 0; off >>= 1) {
    li += __shfl_down(li, off, 64);
    lo += __shfl_down(lo, off, 64);
  }
  __shared__ double lds_i[4], lds_o[4];
  if ((tid & 63) == 0) {
    lds_i[tid >> 6] = li;
    lds_o[tid >> 6] = lo;
  }
  __syncthreads();
  if (tid == 0) {
    const double si = lds_i[0] + lds_i[1] + lds_i[2] + lds_i[3];
    const double so = lds_o[0] + lds_o[1] + lds_o[2] + lds_o[3];
    const float intra = (float)(si / (double)ws->cnt);
    const float outer = (float)(so / (double)(NROW * KSEL));
    out[0] = intra;
    out[1] = intra;
    out[2] = outer;
  }
}

extern "C" void kernel_launch(void* const* d_in, const int* in_sizes, int n_in,
                              void* d_out, int out_size, void* d_ws,
                              size_t ws_size, hipStream_t stream) {
  const float* outputs = (const float*)d_in[0];  // (4,1024,9) f32
  const float* targets = (const float*)d_in[1];  // (4,1024,9) f32
  const int* mask = (const int*)d_in[2];         // (4,1024)
  Ws* ws = (Ws*)d_ws;
  float* out = (float*)d_out;

  stats_kernel<<<NROW / 256, 256, 0, stream>>>(targets, mask, ws);
  prep_kernel<<<(BB * NN) / 256, 256, 0, stream>>>(outputs, ws);
  dist_kernel<<<NBLK, 256, 0, stream>>>(outputs, targets, mask, ws);
  finalize_kernel<<<1, 256, 0, stream>>>(ws, out);
}